// Round 4
// baseline (2122.945 us; speedup 1.0000x reference)
//
#include <hip/hip_runtime.h>
#include <hip/hip_bf16.h>

#define B_   512
#define N_   128
#define H_   256
#define NH_  8
#define HD_  32
#define DEG_ 8
#define R_   (B_ * N_)          // 65536 rows
#define E_   (B_ * N_ * DEG_)   // 524288 edges
#define EPG_ (N_ * DEG_)        // 1024 edges per graph

typedef unsigned short u16;
typedef unsigned int u32;

__device__ __forceinline__ float b2f(u16 u) {
  union { u32 i; float f; } v;
  v.i = ((u32)u) << 16;
  return v.f;
}
__device__ __forceinline__ u16 f2b(float f) {
  union { float f; u32 u; } v;
  v.f = f;
  u32 r = (v.u + 0x7fffu + ((v.u >> 16) & 1u)) >> 16;  // RNE
  return (u16)r;
}

// dtype-generic scalar/vec4 load-store (T = float | u16-as-bf16)
__device__ __forceinline__ float ldv(float x) { return x; }
__device__ __forceinline__ float ldv(u16 x) { return b2f(x); }
__device__ __forceinline__ void ld4(const float* p, float* o) {
  float4 v = *(const float4*)p;
  o[0] = v.x; o[1] = v.y; o[2] = v.z; o[3] = v.w;
}
__device__ __forceinline__ void ld4(const u16* p, float* o) {
  ushort4 v = *(const ushort4*)p;
  o[0] = b2f(v.x); o[1] = b2f(v.y); o[2] = b2f(v.z); o[3] = b2f(v.w);
}
__device__ __forceinline__ void st4(float* p, const float* s) {
  *(float4*)p = make_float4(s[0], s[1], s[2], s[3]);
}
__device__ __forceinline__ void st4(u16* p, const float* s) {
  ushort4 v;
  v.x = f2b(s[0]); v.y = f2b(s[1]); v.z = f2b(s[2]); v.w = f2b(s[3]);
  *(ushort4*)p = v;
}

template <typename T>
__device__ __forceinline__ bool skip(const int* flag) {
  return flag[0] != (sizeof(T) == 2 ? 1 : 0);
}

// stats layout (floats, at d_ws + 0):
//   0..255 sum_local | 256..511 sq_local | 512..767 sum_attn | 768..1023 sq_attn
//   1024..1279 sum_out | 1280..1535 sq_out
//   1536 a_local | 1792 b_local | 2048 a_attn | 2304 b_attn | 2560 a_out | 2816 b_out
//   int at [3072]: dtype flag (1 = bf16, 0 = fp32)

__global__ void zero_stats(float* __restrict__ st) {
  st[blockIdx.x * 256 + threadIdx.x] = 0.f;
}

// Probe: low u16 of each u32 word of h. bf16 data -> valid bf16 (sane exponent
// ~always). fp32 data -> random mantissa bits (sane exponent ~15%).
__global__ void probe_kernel(const u32* __restrict__ hw, int* __restrict__ flag) {
  const int t = threadIdx.x;
  int sane = 0;
  for (int i = t; i < 1024; i += 256) {
    const u16 lo = (u16)(hw[i] & 0xffffu);
    const int e = (lo >> 7) & 0xff;
    if (e == 0 || (e >= 96 && e <= 132)) sane++;
  }
  __shared__ int ssane;
  if (t == 0) ssane = 0;
  __syncthreads();
  atomicAdd(&ssane, sane);
  __syncthreads();
  if (t == 0) flag[0] = (ssane >= 512) ? 1 : 0;
}

// ---------------------------------------------------------------------------
// Edge aggregation: per-graph CSR in LDS, z = h + segment_sum(h[src], dst).
// ---------------------------------------------------------------------------
template <typename T>
__global__ __launch_bounds__(256) void agg_kernel(
    const int* __restrict__ flag, const T* __restrict__ h,
    const int* __restrict__ esrc, const int* __restrict__ edst,
    T* __restrict__ z) {
  if (skip<T>(flag)) return;
  __shared__ int s_src[EPG_];
  __shared__ int s_cnt[N_];
  __shared__ int s_off[N_ + 1];
  __shared__ int s_pos[N_];
  const int g = blockIdx.x;
  const int t = threadIdx.x;

  if (t < N_) s_cnt[t] = 0;
  __syncthreads();

  int dst_loc[4], src_glob[4];
  const int ebase = g * EPG_;
#pragma unroll
  for (int i = 0; i < 4; i++) {
    const int e = ebase + t + i * 256;
    src_glob[i] = esrc[e];
    dst_loc[i] = edst[e] - g * N_;
    atomicAdd(&s_cnt[dst_loc[i]], 1);
  }
  __syncthreads();
  if (t == 0) {
    int acc = 0;
    for (int i = 0; i < N_; i++) { s_off[i] = acc; acc += s_cnt[i]; }
    s_off[N_] = acc;
  }
  __syncthreads();
  if (t < N_) s_pos[t] = s_off[t];
  __syncthreads();
#pragma unroll
  for (int i = 0; i < 4; i++) {
    const int slot = atomicAdd(&s_pos[dst_loc[i]], 1);
    s_src[slot] = src_glob[i];
  }
  __syncthreads();

  const int col = t;
  for (int i = 0; i < N_; i++) {
    const int row = g * N_ + i;
    float acc = ldv(h[(size_t)row * H_ + col]);
    const int e0 = s_off[i], e1 = s_off[i + 1];
    for (int e = e0; e < e1; e++)
      acc += ldv(h[(size_t)s_src[e] * H_ + col]);
    if (sizeof(T) == 2) ((u16*)z)[(size_t)row * H_ + col] = f2b(acc);
    else ((float*)z)[(size_t)row * H_ + col] = acc;
  }
}

// ---------------------------------------------------------------------------
// GEMM, fp32 accumulate: C = act(A[R,K] @ W[NC,K]^T + bias) (+ res)
// ASPLIT: A split into two [R,256] halves. CSPLIT: C split into two halves.
// STATS: deterministic per-column sum/sumsq -> global atomics on zeroed bufs.
// ---------------------------------------------------------------------------
template <typename T, int NC, int K, int RELU, int RES, int STATS, int ASPLIT, int CSPLIT>
__global__ __launch_bounds__(256) void gemm_kernel(
    const int* __restrict__ flag, const T* A, const T* A2,
    const T* __restrict__ W, const T* __restrict__ bias,
    const T* res, T* C, T* C2,
    float* __restrict__ gsum, float* __restrict__ gsq) {
  if (skip<T>(flag)) return;
  __shared__ float At[32][68];
  __shared__ float Wt[32][68];
  __shared__ float red[16][64];

  const int t = threadIdx.x;
  const int ty = t >> 4, tx = t & 15;
  const int row0 = blockIdx.x * 64, col0 = blockIdx.y * 64;

  float acc[4][4] = {};

  for (int kt = 0; kt < K; kt += 32) {
    const T* Abase = (!ASPLIT || kt < 256) ? A : A2;
    const int kbase = (!ASPLIT || kt < 256) ? kt : (kt - 256);
    const int astr = ASPLIT ? 256 : K;
#pragma unroll
    for (int i = 0; i < 2; i++) {
      const int fid = t + i * 256;     // 0..511
      const int r = fid >> 3;          // 0..63
      const int k4 = (fid & 7) * 4;    // 0..28
      float av[4], wv[4];
      ld4(Abase + (size_t)(row0 + r) * astr + kbase + k4, av);
      ld4(W + (size_t)(col0 + r) * K + kt + k4, wv);
      At[k4 + 0][r] = av[0]; At[k4 + 1][r] = av[1];
      At[k4 + 2][r] = av[2]; At[k4 + 3][r] = av[3];
      Wt[k4 + 0][r] = wv[0]; Wt[k4 + 1][r] = wv[1];
      Wt[k4 + 2][r] = wv[2]; Wt[k4 + 3][r] = wv[3];
    }
    __syncthreads();
#pragma unroll
    for (int kk = 0; kk < 32; kk++) {
      const float4 a4 = *(const float4*)&At[kk][ty * 4];
      const float4 w4 = *(const float4*)&Wt[kk][tx * 4];
      const float a[4] = {a4.x, a4.y, a4.z, a4.w};
      const float w[4] = {w4.x, w4.y, w4.z, w4.w};
#pragma unroll
      for (int i = 0; i < 4; i++)
#pragma unroll
        for (int j = 0; j < 4; j++)
          acc[i][j] = fmaf(a[i], w[j], acc[i][j]);
    }
    __syncthreads();
  }

  const int col = col0 + tx * 4;
  float b4[4];
  ld4(bias + col, b4);

  T* Cb;
  int cloc, cstr;
  if (CSPLIT) {
    cstr = 256;
    if (col < 256) { Cb = C; cloc = col; } else { Cb = C2; cloc = col - 256; }
  } else {
    Cb = C; cloc = col; cstr = NC;
  }

  float sj[4] = {}, qj[4] = {};
#pragma unroll
  for (int i = 0; i < 4; i++) {
    const int row = row0 + ty * 4 + i;
    float rv[4] = {0.f, 0.f, 0.f, 0.f};
    if (RES) ld4(res + (size_t)row * NC + col, rv);
    float v[4];
#pragma unroll
    for (int j = 0; j < 4; j++) {
      float val = acc[i][j] + b4[j];
      if (RELU) val = fmaxf(val, 0.f);
      if (RES) val += rv[j];
      v[j] = val;
      if (STATS) { sj[j] += val; qj[j] += val * val; }
    }
    st4(Cb + (size_t)row * cstr + cloc, v);
  }

  if (STATS) {
    __syncthreads();
#pragma unroll
    for (int j = 0; j < 4; j++) red[ty][tx * 4 + j] = sj[j];
    __syncthreads();
    if (t < 64) {
      float s = 0.f;
#pragma unroll
      for (int yy = 0; yy < 16; yy++) s += red[yy][t];
      atomicAdd(&gsum[col0 + t], s);
    }
    __syncthreads();
#pragma unroll
    for (int j = 0; j < 4; j++) red[ty][tx * 4 + j] = qj[j];
    __syncthreads();
    if (t < 64) {
      float s = 0.f;
#pragma unroll
      for (int yy = 0; yy < 16; yy++) s += red[yy][t];
      atomicAdd(&gsq[col0 + t], s);
    }
  }
}

// ---------------------------------------------------------------------------
// Attention: one block per (graph, head). o may alias q (full stage first;
// each block touches only its own (g,head) rectangle).
// ---------------------------------------------------------------------------
template <typename T>
__global__ __launch_bounds__(256) void attn_kernel(
    const int* __restrict__ flag, const T* q, const T* __restrict__ k,
    const T* __restrict__ v, T* o) {
  if (skip<T>(flag)) return;
  __shared__ float qs[N_][33];
  __shared__ float ks[N_][33];
  __shared__ float vs[N_][33];
  __shared__ float attb[4][N_];

  const int g = blockIdx.x >> 3;
  const int hd = blockIdx.x & 7;
  const int t = threadIdx.x;
  const int base_col = hd * HD_;

#pragma unroll
  for (int i = 0; i < 4; i++) {
    const int fid = t + i * 256;       // 0..1023
    const int row = fid >> 3;
    const int c4 = (fid & 7) * 4;
    const size_t gidx = (size_t)(g * N_ + row) * H_ + base_col + c4;
    float qv[4], kv[4], vv[4];
    ld4(q + gidx, qv);
    ld4(k + gidx, kv);
    ld4(v + gidx, vv);
#pragma unroll
    for (int j = 0; j < 4; j++) {
      qs[row][c4 + j] = qv[j];
      ks[row][c4 + j] = kv[j];
      vs[row][c4 + j] = vv[j];
    }
  }
  __syncthreads();

  const int wave = t >> 6, lane = t & 63;
  const float scale = 0.1767766952966369f;  // 1/sqrt(32)

  for (int qr = wave; qr < N_; qr += 4) {  // uniform trip count
    float s0 = 0.f, s1 = 0.f;
#pragma unroll
    for (int d = 0; d < HD_; d++) {
      const float qd = qs[qr][d];
      s0 = fmaf(qd, ks[lane][d], s0);
      s1 = fmaf(qd, ks[64 + lane][d], s1);
    }
    s0 *= scale; s1 *= scale;
    float m = fmaxf(s0, s1);
#pragma unroll
    for (int off = 32; off; off >>= 1) m = fmaxf(m, __shfl_xor(m, off));
    const float e0 = __expf(s0 - m), e1 = __expf(s1 - m);
    float sum = e0 + e1;
#pragma unroll
    for (int off = 32; off; off >>= 1) sum += __shfl_xor(sum, off);
    const float inv = 1.f / sum;
    attb[wave][lane] = e0 * inv;
    attb[wave][64 + lane] = e1 * inv;
    __syncthreads();

    const int d = lane & 31, half = lane >> 5;
    const float* ab = attb[wave];
    float acc = 0.f;
    const int j0 = half * 64;
    for (int j = j0; j < j0 + 64; j++) acc = fmaf(ab[j], vs[j][d], acc);
    acc += __shfl_xor(acc, 32);
    if (half == 0) {
      const size_t oi = (size_t)(g * N_ + qr) * H_ + base_col + d;
      if (sizeof(T) == 2) ((u16*)o)[oi] = f2b(acc);
      else ((float*)o)[oi] = acc;
    }
    __syncthreads();
  }
}

template <typename T>
__global__ void bn_finalize(const int* __restrict__ flag,
                            const float* __restrict__ sum,
                            const float* __restrict__ sq,
                            const T* __restrict__ g,
                            const T* __restrict__ bb,
                            float* __restrict__ a, float* __restrict__ b) {
  if (skip<T>(flag)) return;
  const int c = threadIdx.x;
  const float mean = sum[c] * (1.f / R_);
  const float var = fmaxf(sq[c] * (1.f / R_) - mean * mean, 0.f);
  const float ai = ldv(g[c]) * rsqrtf(var + 1e-5f);
  a[c] = ai;
  b[c] = ldv(bb[c]) - mean * ai;
}

// x = bn_local(r_local) + bn_attn(r_attn)
template <typename T>
__global__ __launch_bounds__(256) void combine_kernel(
    const int* __restrict__ flag, const T* __restrict__ rl,
    const T* __restrict__ ra, const float* __restrict__ st,
    T* __restrict__ x) {
  if (skip<T>(flag)) return;
  const size_t i = (size_t)blockIdx.x * 256 + threadIdx.x;  // 4-elem group idx
  const int col = (int)(i & 63) * 4;
  float rl4[4], ra4[4];
  ld4(rl + i * 4, rl4);
  ld4(ra + i * 4, ra4);
  const float* al = st + 1536;
  const float* bl = st + 1792;
  const float* aa = st + 2048;
  const float* ba = st + 2304;
  float o[4];
#pragma unroll
  for (int j = 0; j < 4; j++)
    o[j] = al[col + j] * rl4[j] + bl[col + j] + aa[col + j] * ra4[j] + ba[col + j];
  st4(x + i * 4, o);
}

// out = bn_out(y)
template <typename T>
__global__ __launch_bounds__(256) void final_kernel(
    const int* __restrict__ flag, const T* __restrict__ y,
    const float* __restrict__ st, T* __restrict__ out) {
  if (skip<T>(flag)) return;
  const size_t i = (size_t)blockIdx.x * 256 + threadIdx.x;
  const int col = (int)(i & 63) * 4;
  float y4[4];
  ld4(y + i * 4, y4);
  const float* ao = st + 2560;
  const float* bo = st + 2816;
  float o[4];
#pragma unroll
  for (int j = 0; j < 4; j++) o[j] = ao[col + j] * y4[j] + bo[col + j];
  st4(out + i * 4, o);
}

// ---------------------------------------------------------------------------
template <typename T>
static void run_pipeline(const int* flag, const T* h, const int* esrc,
                         const int* edst, void* const* d_in, float* stats,
                         T* S1, T* S2, T* OD, hipStream_t stream) {
  const T* gin_w1 = (const T*)d_in[3];
  const T* gin_b1 = (const T*)d_in[4];
  const T* gin_w2 = (const T*)d_in[5];
  const T* gin_b2 = (const T*)d_in[6];
  const T* attn_in_w = (const T*)d_in[7];
  const T* attn_in_b = (const T*)d_in[8];
  const T* attn_out_w = (const T*)d_in[9];
  const T* attn_out_b = (const T*)d_in[10];
  const T* bn_local_g = (const T*)d_in[11];
  const T* bn_local_b = (const T*)d_in[12];
  const T* bn_attn_g = (const T*)d_in[13];
  const T* bn_attn_b = (const T*)d_in[14];
  const T* bn_out_g = (const T*)d_in[15];
  const T* bn_out_b = (const T*)d_in[16];
  const T* ffn1_w = (const T*)d_in[17];
  const T* ffn1_b = (const T*)d_in[18];
  const T* ffn2_w = (const T*)d_in[19];
  const T* ffn2_b = (const T*)d_in[20];

  const size_t RH = (size_t)R_ * H_;
  const dim3 gg(R_ / 64, 4), gg2(R_ / 64, 8);

  // q -> S1, k -> S2, v -> OD
  gemm_kernel<T, 256, 256, 0, 0, 0, 0, 0><<<gg, 256, 0, stream>>>(
      flag, h, nullptr, attn_in_w, attn_in_b, nullptr, S1, nullptr, nullptr, nullptr);
  gemm_kernel<T, 256, 256, 0, 0, 0, 0, 0><<<gg, 256, 0, stream>>>(
      flag, h, nullptr, attn_in_w + 256 * 256, attn_in_b + 256, nullptr, S2, nullptr, nullptr, nullptr);
  gemm_kernel<T, 256, 256, 0, 0, 0, 0, 0><<<gg, 256, 0, stream>>>(
      flag, h, nullptr, attn_in_w + 512 * 256, attn_in_b + 512, nullptr, OD, nullptr, nullptr, nullptr);
  // o over q (S1)
  attn_kernel<T><<<B_ * NH_, 256, 0, stream>>>(flag, S1, S2, OD, S1);
  // r_attn = h + o@Wo -> S2, stats_attn
  gemm_kernel<T, 256, 256, 0, 1, 1, 0, 0><<<gg, 256, 0, stream>>>(
      flag, S1, nullptr, attn_out_w, attn_out_b, h, S2, nullptr, stats + 512, stats + 768);
  // z -> OD
  agg_kernel<T><<<B_, 256, 0, stream>>>(flag, h, esrc, edst, OD);
  // t1 = relu(z@W1) -> S1
  gemm_kernel<T, 256, 256, 1, 0, 0, 0, 0><<<gg, 256, 0, stream>>>(
      flag, OD, nullptr, gin_w1, gin_b1, nullptr, S1, nullptr, nullptr, nullptr);
  // r_local = h + t1@W2 -> OD, stats_local
  gemm_kernel<T, 256, 256, 0, 1, 1, 0, 0><<<gg, 256, 0, stream>>>(
      flag, S1, nullptr, gin_w2, gin_b2, h, OD, nullptr, stats + 0, stats + 256);

  bn_finalize<T><<<1, 256, 0, stream>>>(flag, stats + 0, stats + 256,
                                        bn_local_g, bn_local_b, stats + 1536, stats + 1792);
  bn_finalize<T><<<1, 256, 0, stream>>>(flag, stats + 512, stats + 768,
                                        bn_attn_g, bn_attn_b, stats + 2048, stats + 2304);

  // x = bn_l(r_local OD) + bn_a(r_attn S2) -> S1
  combine_kernel<T><<<(int)(RH / 4 / 256), 256, 0, stream>>>(flag, OD, S2, stats, S1);
  // t2 = relu(x@F1): lo -> S2, hi -> OD
  gemm_kernel<T, 512, 256, 1, 0, 0, 0, 1><<<gg2, 256, 0, stream>>>(
      flag, S1, nullptr, ffn1_w, ffn1_b, nullptr, S2, OD, nullptr, nullptr);
  // y = x + t2@F2 -> S1 in place, stats_out
  gemm_kernel<T, 256, 512, 0, 1, 1, 1, 0><<<gg, 256, 0, stream>>>(
      flag, S2, OD, ffn2_w, ffn2_b, S1, S1, nullptr, stats + 1024, stats + 1280);

  bn_finalize<T><<<1, 256, 0, stream>>>(flag, stats + 1024, stats + 1280,
                                        bn_out_g, bn_out_b, stats + 2560, stats + 2816);
  // out = bn_out(y S1) -> OD (= d_out)
  final_kernel<T><<<(int)(RH / 4 / 256), 256, 0, stream>>>(flag, S1, stats, OD);
}

extern "C" void kernel_launch(void* const* d_in, const int* in_sizes, int n_in,
                              void* d_out, int out_size, void* d_ws, size_t ws_size,
                              hipStream_t stream) {
  const int* esrc = (const int*)d_in[1];
  const int* edst = (const int*)d_in[2];

  float* stats = (float*)d_ws;                 // 3072 floats + flag
  int* flag = (int*)(stats + 3072);
  char* slotA = (char*)d_ws + 65536;           // 64 MB slot
  char* slotB = slotA + ((size_t)R_ * H_ * 4); // 64 MB slot

  zero_stats<<<12, 256, 0, stream>>>(stats);
  probe_kernel<<<1, 256, 0, stream>>>((const u32*)d_in[0], flag);

  // bf16 pipeline (runs iff flag==1)
  run_pipeline<u16>(flag, (const u16*)d_in[0], esrc, edst, d_in, stats,
                    (u16*)slotA, (u16*)slotB, (u16*)d_out, stream);
  // fp32 pipeline (runs iff flag==0)
  run_pipeline<float>(flag, (const float*)d_in[0], esrc, edst, d_in, stats,
                      (float*)slotA, (float*)slotB, (float*)d_out, stream);
}

// Round 6
// 1270.188 us; speedup vs baseline: 1.6714x; 1.6714x over previous
//
#include <hip/hip_runtime.h>
#include <hip/hip_bf16.h>

#define B_   512
#define N_   128
#define H_   256
#define NH_  8
#define HD_  32
#define DEG_ 8
#define R_   (B_ * N_)          // 65536 rows
#define E_   (B_ * N_ * DEG_)   // 524288 edges
#define EPG_ (N_ * DEG_)        // 1024 edges per graph

typedef unsigned short u16;
typedef unsigned int u32;

typedef __attribute__((ext_vector_type(8))) short s16x8;   // 8 bf16 = 4 VGPRs
typedef __attribute__((ext_vector_type(4))) float f32x4;   // MFMA acc

__device__ __forceinline__ float b2f(u16 u) {
  union { u32 i; float f; } v;
  v.i = ((u32)u) << 16;
  return v.f;
}
__device__ __forceinline__ u16 f2b(float f) {
  union { float f; u32 u; } v;
  v.f = f;
  u32 r = (v.u + 0x7fffu + ((v.u >> 16) & 1u)) >> 16;  // RNE
  return (u16)r;
}
__device__ __forceinline__ void ld4b(const u16* p, float* o) {
  ushort4 v = *(const ushort4*)p;
  o[0] = b2f(v.x); o[1] = b2f(v.y); o[2] = b2f(v.z); o[3] = b2f(v.w);
}

// stats layout (floats, at d_ws + 0):
//   0..255 sum_local | 256..511 sq_local | 512..767 sum_attn | 768..1023 sq_attn
//   1024..1279 sum_out | 1280..1535 sq_out
//   1536 a_local | 1792 b_local | 2048 a_attn | 2304 b_attn | 2560 a_out | 2816 b_out

// packed bf16 weight area offsets (u16 elements)
#define OFF_GW1 0
#define OFF_GB1 65536
#define OFF_GW2 65792
#define OFF_GB2 131328
#define OFF_AIW 131584
#define OFF_AIB 328192
#define OFF_AOW 328960
#define OFF_AOB 394496
#define OFF_F1W 394752
#define OFF_F1B 525824
#define OFF_F2W 526336
#define OFF_F2B 657408
#define W_TOTAL 657664

__global__ void zero_stats(float* __restrict__ st) {
  st[blockIdx.x * 256 + threadIdx.x] = 0.f;
}

// fp32 -> bf16 for h (grid covers R_*H_/4)
__global__ __launch_bounds__(256) void cvt_h(const float* __restrict__ src,
                                             u16* __restrict__ dst) {
  const size_t i = ((size_t)blockIdx.x * 256 + threadIdx.x) * 4;
  const float4 v = *(const float4*)(src + i);
  ushort4 o;
  o.x = f2b(v.x); o.y = f2b(v.y); o.z = f2b(v.z); o.w = f2b(v.w);
  *(ushort4*)(dst + i) = o;
}

// fp32 -> bf16 for the 12 weight/bias tensors, packed
__global__ __launch_bounds__(256) void cvt_w(
    const float* s0, const float* s1, const float* s2, const float* s3,
    const float* s4, const float* s5, const float* s6, const float* s7,
    const float* s8, const float* s9, const float* s10, const float* s11,
    u16* __restrict__ dst) {
  const int sizes[12] = {65536, 256, 65536, 256, 196608, 768,
                         65536, 256, 131072, 512, 131072, 256};
  const float* srcs[12] = {s0, s1, s2, s3, s4, s5, s6, s7, s8, s9, s10, s11};
  int gid = (blockIdx.x * 256 + threadIdx.x) * 4;
  if (gid >= W_TOTAL) return;
  int seg = 0, off = gid;
  while (off >= sizes[seg]) { off -= sizes[seg]; seg++; }
  const float4 v = *(const float4*)(srcs[seg] + off);
  ushort4 o;
  o.x = f2b(v.x); o.y = f2b(v.y); o.z = f2b(v.z); o.w = f2b(v.w);
  *(ushort4*)(dst + gid) = o;
}

// ---------------------------------------------------------------------------
// Edge aggregation: per-graph CSR in LDS, z = h + segment_sum(h[src], dst).
// ---------------------------------------------------------------------------
__global__ __launch_bounds__(256) void agg_kernel(
    const u16* __restrict__ h, const int* __restrict__ esrc,
    const int* __restrict__ edst, u16* __restrict__ z) {
  __shared__ int s_src[EPG_];
  __shared__ int s_cnt[N_];
  __shared__ int s_off[N_ + 1];
  __shared__ int s_pos[N_];
  const int g = blockIdx.x;
  const int t = threadIdx.x;

  if (t < N_) s_cnt[t] = 0;
  __syncthreads();

  int dst_loc[4], src_glob[4];
  const int ebase = g * EPG_;
#pragma unroll
  for (int i = 0; i < 4; i++) {
    const int e = ebase + t + i * 256;
    src_glob[i] = esrc[e];
    dst_loc[i] = edst[e] - g * N_;
    atomicAdd(&s_cnt[dst_loc[i]], 1);
  }
  __syncthreads();
  if (t == 0) {
    int acc = 0;
    for (int i = 0; i < N_; i++) { s_off[i] = acc; acc += s_cnt[i]; }
    s_off[N_] = acc;
  }
  __syncthreads();
  if (t < N_) s_pos[t] = s_off[t];
  __syncthreads();
#pragma unroll
  for (int i = 0; i < 4; i++) {
    const int slot = atomicAdd(&s_pos[dst_loc[i]], 1);
    s_src[slot] = src_glob[i];
  }
  __syncthreads();

  const int col = t;
  for (int i = 0; i < N_; i++) {
    const int row = g * N_ + i;
    float acc = b2f(h[(size_t)row * H_ + col]);
    const int e0 = s_off[i], e1 = s_off[i + 1];
    for (int e = e0; e < e1; e++)
      acc += b2f(h[(size_t)s_src[e] * H_ + col]);
    z[(size_t)row * H_ + col] = f2b(acc);
  }
}

// ---------------------------------------------------------------------------
// MFMA bf16 GEMM (m97 structure): C = act(A[R,K] @ W[NC,K]^T + bias) (+res)
// 128x128 tile, 256 thr = 4 waves (2x2), BK=64, global_load_lds 16B staging.
// ASPLIT: A = two [R,256] halves (K==512). CMODE: C split into 256-col chunks
// C0/C1/C2. RES: res is [R,256] bf16 (requires NC==256). STATS: per-column
// sum/sumsq via shfl + global atomics onto zeroed buffers.
// ---------------------------------------------------------------------------
template <int NC, int K, int RELU, int RES, int STATS, int ASPLIT, int CMODE>
__global__ __launch_bounds__(256) void gemm_mfma(
    const u16* A, const u16* A2,
    const u16* __restrict__ W, const u16* __restrict__ bias,
    const u16* res, u16* C0, u16* C1, u16* C2,
    float* __restrict__ gsum, float* __restrict__ gsq) {
  __shared__ u16 As[128 * 64] __attribute__((aligned(16)));
  __shared__ u16 Bs[128 * 64] __attribute__((aligned(16)));

  const int t = threadIdx.x;
  const int wave = t >> 6, lane = t & 63;
  const int wr = wave >> 1, wc = wave & 1;
  const int quad = lane >> 4, ln15 = lane & 15;
  const int row0 = blockIdx.x * 128, col0 = blockIdx.y * 128;

  f32x4 acc[4][4];
#pragma unroll
  for (int i = 0; i < 4; i++)
#pragma unroll
    for (int j = 0; j < 4; j++) acc[i][j] = (f32x4){0.f, 0.f, 0.f, 0.f};

  for (int kt = 0; kt < K; kt += 64) {
    const u16* Ab;
    int kb, astr;
    if (ASPLIT) {
      if (kt < 256) { Ab = A; kb = kt; } else { Ab = A2; kb = kt - 256; }
      astr = 256;
    } else {
      Ab = A; kb = kt; astr = K;
    }
#pragma unroll
    for (int i = 0; i < 4; i++) {
      const int fid = t + i * 256;  // 0..1023: row = fid>>3, 16B seg = fid&7
      const u16* ga = Ab + (size_t)(row0 + (fid >> 3)) * astr + kb + (fid & 7) * 8;
      __builtin_amdgcn_global_load_lds(
          (const __attribute__((address_space(1))) void*)ga,
          (__attribute__((address_space(3))) void*)(As + fid * 8), 16, 0, 0);
      const u16* gw = W + (size_t)(col0 + (fid >> 3)) * K + kt + (fid & 7) * 8;
      __builtin_amdgcn_global_load_lds(
          (const __attribute__((address_space(1))) void*)gw,
          (__attribute__((address_space(3))) void*)(Bs + fid * 8), 16, 0, 0);
    }
    __syncthreads();
#pragma unroll
    for (int ks = 0; ks < 64; ks += 32) {
      s16x8 af[4], bf[4];
#pragma unroll
      for (int i = 0; i < 4; i++)
        af[i] = *(const s16x8*)(As + (wr * 64 + i * 16 + ln15) * 64 + ks + quad * 8);
#pragma unroll
      for (int j = 0; j < 4; j++)
        bf[j] = *(const s16x8*)(Bs + (wc * 64 + j * 16 + ln15) * 64 + ks + quad * 8);
#pragma unroll
      for (int i = 0; i < 4; i++)
#pragma unroll
        for (int j = 0; j < 4; j++)
          acc[i][j] = __builtin_amdgcn_mfma_f32_16x16x32_bf16(af[i], bf[j], acc[i][j], 0, 0, 0);
    }
    __syncthreads();
  }

  // ---- epilogue ----
  const int cbase = col0 + wc * 64;  // + j*16 + ln15 = global col
  u16* Cb;
  int coff, cstr;
  if (CMODE) {
    const int chunk = col0 >> 8;
    Cb = (chunk == 0) ? C0 : ((chunk == 1) ? C1 : C2);
    coff = (col0 & 255) + wc * 64;
    cstr = 256;
  } else {
    Cb = C0; coff = cbase; cstr = NC;
  }

  float bs[4];
#pragma unroll
  for (int j = 0; j < 4; j++) bs[j] = b2f(bias[cbase + j * 16 + ln15]);

  float ssum[4] = {}, ssq[4] = {};
#pragma unroll
  for (int i = 0; i < 4; i++) {
    const int rbase = row0 + wr * 64 + i * 16 + quad * 4;
#pragma unroll
    for (int reg = 0; reg < 4; reg++) {
      const int row = rbase + reg;
#pragma unroll
      for (int j = 0; j < 4; j++) {
        float val = acc[i][j][reg] + bs[j];
        if (RELU) val = fmaxf(val, 0.f);
        if (RES) val += b2f(res[(size_t)row * 256 + cbase + j * 16 + ln15]);
        Cb[(size_t)row * cstr + coff + j * 16 + ln15] = f2b(val);
        if (STATS) { ssum[j] += val; ssq[j] += val * val; }
      }
    }
  }

  if (STATS) {
#pragma unroll
    for (int j = 0; j < 4; j++) {
      float s = ssum[j];
      s += __shfl_xor(s, 16);
      s += __shfl_xor(s, 32);
      float q = ssq[j];
      q += __shfl_xor(q, 16);
      q += __shfl_xor(q, 32);
      if (lane < 16) {
        atomicAdd(&gsum[cbase + j * 16 + lane], s);
        atomicAdd(&gsq[cbase + j * 16 + lane], q);
      }
    }
  }
}

// ---------------------------------------------------------------------------
// Attention (structure verified passing in R4): one block per (graph, head).
// o may alias q (block reads exactly the rectangle it writes, staged first).
// ---------------------------------------------------------------------------
__global__ __launch_bounds__(256) void attn_kernel(
    const u16* q, const u16* __restrict__ k,
    const u16* __restrict__ v, u16* o) {
  __shared__ float qs[N_][33];
  __shared__ float ks[N_][33];
  __shared__ float vs[N_][33];
  __shared__ float attb[4][N_];

  const int g = blockIdx.x >> 3;
  const int hd = blockIdx.x & 7;
  const int t = threadIdx.x;
  const int base_col = hd * HD_;

#pragma unroll
  for (int i = 0; i < 4; i++) {
    const int fid = t + i * 256;       // 0..1023
    const int row = fid >> 3;
    const int c4 = (fid & 7) * 4;
    const size_t gidx = (size_t)(g * N_ + row) * H_ + base_col + c4;
    float qv[4], kv[4], vv[4];
    ld4b(q + gidx, qv);
    ld4b(k + gidx, kv);
    ld4b(v + gidx, vv);
#pragma unroll
    for (int j = 0; j < 4; j++) {
      qs[row][c4 + j] = qv[j];
      ks[row][c4 + j] = kv[j];
      vs[row][c4 + j] = vv[j];
    }
  }
  __syncthreads();

  const int wave = t >> 6, lane = t & 63;
  const float scale = 0.1767766952966369f;  // 1/sqrt(32)

  for (int qr = wave; qr < N_; qr += 4) {  // uniform trip count
    float s0 = 0.f, s1 = 0.f;
#pragma unroll
    for (int d = 0; d < HD_; d++) {
      const float qd = qs[qr][d];
      s0 = fmaf(qd, ks[lane][d], s0);
      s1 = fmaf(qd, ks[64 + lane][d], s1);
    }
    s0 *= scale; s1 *= scale;
    float m = fmaxf(s0, s1);
#pragma unroll
    for (int off = 32; off; off >>= 1) m = fmaxf(m, __shfl_xor(m, off));
    const float e0 = __expf(s0 - m), e1 = __expf(s1 - m);
    float sum = e0 + e1;
#pragma unroll
    for (int off = 32; off; off >>= 1) sum += __shfl_xor(sum, off);
    const float inv = 1.f / sum;
    attb[wave][lane] = e0 * inv;
    attb[wave][64 + lane] = e1 * inv;
    __syncthreads();

    const int d = lane & 31, half = lane >> 5;
    const float* ab = attb[wave];
    float acc = 0.f;
    const int j0 = half * 64;
    for (int j = j0; j < j0 + 64; j++) acc = fmaf(ab[j], vs[j][d], acc);
    acc += __shfl_xor(acc, 32);
    if (half == 0)
      o[(size_t)(g * N_ + qr) * H_ + base_col + d] = f2b(acc);
    __syncthreads();
  }
}

// BN finalize: a = g*rsqrt(var+eps); b' = b - mean*a   (fp32 params)
__global__ void bn_finalize(const float* __restrict__ sum,
                            const float* __restrict__ sq,
                            const float* __restrict__ g,
                            const float* __restrict__ bb,
                            float* __restrict__ a, float* __restrict__ b) {
  const int c = threadIdx.x;
  const float mean = sum[c] * (1.f / R_);
  const float var = fmaxf(sq[c] * (1.f / R_) - mean * mean, 0.f);
  const float ai = g[c] * rsqrtf(var + 1e-5f);
  a[c] = ai;
  b[c] = bb[c] - mean * ai;
}

// x = bn_local(r_local) + bn_attn(r_attn)   (bf16 in/out)
__global__ __launch_bounds__(256) void combine_kernel(
    const u16* __restrict__ rl, const u16* __restrict__ ra,
    const float* __restrict__ st, u16* __restrict__ x) {
  const size_t i = (size_t)blockIdx.x * 256 + threadIdx.x;  // 4-elem group idx
  const int col = (int)(i & 63) * 4;
  float rl4[4], ra4[4];
  ld4b(rl + i * 4, rl4);
  ld4b(ra + i * 4, ra4);
  const float* al = st + 1536;
  const float* bl = st + 1792;
  const float* aa = st + 2048;
  const float* ba = st + 2304;
  ushort4 o;
  u16* ov = (u16*)&o;
#pragma unroll
  for (int j = 0; j < 4; j++)
    ov[j] = f2b(al[col + j] * rl4[j] + bl[col + j] + aa[col + j] * ra4[j] + ba[col + j]);
  *(ushort4*)(x + i * 4) = o;
}

// out = bn_out(y): bf16 y -> fp32 out
__global__ __launch_bounds__(256) void final_kernel(
    const u16* __restrict__ y, const float* __restrict__ st,
    float* __restrict__ out) {
  const size_t i = (size_t)blockIdx.x * 256 + threadIdx.x;
  const int col = (int)(i & 63) * 4;
  float y4[4];
  ld4b(y + i * 4, y4);
  const float* ao = st + 2560;
  const float* bo = st + 2816;
  float4 o;
  o.x = ao[col + 0] * y4[0] + bo[col + 0];
  o.y = ao[col + 1] * y4[1] + bo[col + 1];
  o.z = ao[col + 2] * y4[2] + bo[col + 2];
  o.w = ao[col + 3] * y4[3] + bo[col + 3];
  *(float4*)(out + i * 4) = o;
}

extern "C" void kernel_launch(void* const* d_in, const int* in_sizes, int n_in,
                              void* d_out, int out_size, void* d_ws, size_t ws_size,
                              hipStream_t stream) {
  const float* h = (const float*)d_in[0];
  const int* esrc = (const int*)d_in[1];
  const int* edst = (const int*)d_in[2];
  const float* bn_local_g = (const float*)d_in[11];
  const float* bn_local_b = (const float*)d_in[12];
  const float* bn_attn_g = (const float*)d_in[13];
  const float* bn_attn_b = (const float*)d_in[14];
  const float* bn_out_g = (const float*)d_in[15];
  const float* bn_out_b = (const float*)d_in[16];

  const size_t RH = (size_t)R_ * H_;
  float* stats = (float*)d_ws;                        // 3072 floats
  u16* WB = (u16*)((char*)d_ws + 65536);              // packed bf16 weights ~1.3 MB
  u16* Hb = (u16*)((char*)d_ws + 65536 + 2097152);    // h in bf16, 32 MB
  u16* S1 = Hb + RH;                                  // 32 MB
  u16* S2 = S1 + RH;                                  // 32 MB
  u16* OD = (u16*)d_out;                              // first 32 MB of d_out as bf16 scratch
  float* outf = (float*)d_out;                        // final fp32 out (64 MB)

  zero_stats<<<12, 256, 0, stream>>>(stats);
  cvt_h<<<(int)(RH / 4 / 256), 256, 0, stream>>>(h, Hb);
  cvt_w<<<(W_TOTAL / 4 + 255) / 256, 256, 0, stream>>>(
      (const float*)d_in[3], (const float*)d_in[4], (const float*)d_in[5],
      (const float*)d_in[6], (const float*)d_in[7], (const float*)d_in[8],
      (const float*)d_in[9], (const float*)d_in[10], (const float*)d_in[17],
      (const float*)d_in[18], (const float*)d_in[19], (const float*)d_in[20], WB);

  // qkv fused: [R,768] -> q=S1, k=S2, v=OD
  gemm_mfma<768, 256, 0, 0, 0, 0, 1><<<dim3(512, 6), 256, 0, stream>>>(
      Hb, nullptr, WB + OFF_AIW, WB + OFF_AIB, nullptr, S1, S2, OD, nullptr, nullptr);
  // o = softmax(q k^T / sqrt(32)) v, in-place over q (S1)
  attn_kernel<<<B_ * NH_, 256, 0, stream>>>(S1, S2, OD, S1);
  // r_attn = h + o@Wo^T -> S2, + stats_attn
  gemm_mfma<256, 256, 0, 1, 1, 0, 0><<<dim3(512, 2), 256, 0, stream>>>(
      S1, nullptr, WB + OFF_AOW, WB + OFF_AOB, Hb, S2, nullptr, nullptr,
      stats + 512, stats + 768);
  // z = h + segment_sum -> OD
  agg_kernel<<<B_, 256, 0, stream>>>(Hb, esrc, edst, OD);
  // t1 = relu(z@W1^T) -> S1
  gemm_mfma<256, 256, 1, 0, 0, 0, 0><<<dim3(512, 2), 256, 0, stream>>>(
      OD, nullptr, WB + OFF_GW1, WB + OFF_GB1, nullptr, S1, nullptr, nullptr,
      nullptr, nullptr);
  // r_local = h + t1@W2^T -> OD, + stats_local
  gemm_mfma<256, 256, 0, 1, 1, 0, 0><<<dim3(512, 2), 256, 0, stream>>>(
      S1, nullptr, WB + OFF_GW2, WB + OFF_GB2, Hb, OD, nullptr, nullptr,
      stats + 0, stats + 256);

  bn_finalize<<<1, 256, 0, stream>>>(stats + 0, stats + 256, bn_local_g,
                                     bn_local_b, stats + 1536, stats + 1792);
  bn_finalize<<<1, 256, 0, stream>>>(stats + 512, stats + 768, bn_attn_g,
                                     bn_attn_b, stats + 2048, stats + 2304);

  // x = bn_l(r_local OD) + bn_a(r_attn S2) -> S1
  combine_kernel<<<(int)(RH / 4 / 256), 256, 0, stream>>>(OD, S2, stats, S1);
  // t2 = relu(x@F1^T) [R,512]: lo -> S2, hi -> OD
  gemm_mfma<512, 256, 1, 0, 0, 0, 1><<<dim3(512, 4), 256, 0, stream>>>(
      S1, nullptr, WB + OFF_F1W, WB + OFF_F1B, nullptr, S2, OD, nullptr,
      nullptr, nullptr);
  // y = x + t2@F2^T -> S1 in place, + stats_out
  gemm_mfma<256, 512, 0, 1, 1, 1, 0><<<dim3(512, 2), 256, 0, stream>>>(
      S2, OD, WB + OFF_F2W, WB + OFF_F2B, S1, S1, nullptr, nullptr,
      stats + 1024, stats + 1280);

  bn_finalize<<<1, 256, 0, stream>>>(stats + 1024, stats + 1280, bn_out_g,
                                     bn_out_b, stats + 2560, stats + 2816);
  // out = bn_out(y S1) -> fp32 d_out
  final_kernel<<<(int)(RH / 4 / 256), 256, 0, stream>>>(S1, stats, outf);
}

// Round 7
// 865.145 us; speedup vs baseline: 2.4539x; 1.4682x over previous
//
#include <hip/hip_runtime.h>
#include <hip/hip_bf16.h>

#define B_   512
#define N_   128
#define H_   256
#define NH_  8
#define HD_  32
#define DEG_ 8
#define R_   (B_ * N_)          // 65536 rows
#define E_   (B_ * N_ * DEG_)   // 524288 edges
#define EPG_ (N_ * DEG_)        // 1024 edges per graph

typedef unsigned short u16;
typedef unsigned int u32;

typedef __attribute__((ext_vector_type(8))) short s16x8;   // 8 bf16 = 4 VGPRs
typedef __attribute__((ext_vector_type(4))) float f32x4;   // MFMA acc

__device__ __forceinline__ float b2f(u16 u) {
  union { u32 i; float f; } v;
  v.i = ((u32)u) << 16;
  return v.f;
}
__device__ __forceinline__ u16 f2b(float f) {
  union { float f; u32 u; } v;
  v.f = f;
  u32 r = (v.u + 0x7fffu + ((v.u >> 16) & 1u)) >> 16;  // RNE
  return (u16)r;
}
__device__ __forceinline__ void ld4b(const u16* p, float* o) {
  ushort4 v = *(const ushort4*)p;
  o[0] = b2f(v.x); o[1] = b2f(v.y); o[2] = b2f(v.z); o[3] = b2f(v.w);
}

// stats layout (floats, at d_ws + 0):
//   0..255 sum_local | 256..511 sq_local | 512..767 sum_attn | 768..1023 sq_attn
//   1024..1279 sum_out | 1280..1535 sq_out
//   1536 a_local | 1792 b_local | 2048 a_attn | 2304 b_attn | 2560 a_out | 2816 b_out

// packed bf16 weight area offsets (u16 elements)
#define OFF_GW1 0
#define OFF_GB1 65536
#define OFF_GW2 65792
#define OFF_GB2 131328
#define OFF_AIW 131584
#define OFF_AIB 328192
#define OFF_AOW 328960
#define OFF_AOB 394496
#define OFF_F1W 394752
#define OFF_F1B 525824
#define OFF_F2W 526336
#define OFF_F2B 657408
#define W_TOTAL 657664

__global__ void zero_stats(float* __restrict__ st) {
  st[blockIdx.x * 256 + threadIdx.x] = 0.f;
}

// fp32 -> bf16 for h (grid covers R_*H_/4)
__global__ __launch_bounds__(256) void cvt_h(const float* __restrict__ src,
                                             u16* __restrict__ dst) {
  const size_t i = ((size_t)blockIdx.x * 256 + threadIdx.x) * 4;
  const float4 v = *(const float4*)(src + i);
  ushort4 o;
  o.x = f2b(v.x); o.y = f2b(v.y); o.z = f2b(v.z); o.w = f2b(v.w);
  *(ushort4*)(dst + i) = o;
}

// fp32 -> bf16 for the 12 weight/bias tensors, packed
__global__ __launch_bounds__(256) void cvt_w(
    const float* s0, const float* s1, const float* s2, const float* s3,
    const float* s4, const float* s5, const float* s6, const float* s7,
    const float* s8, const float* s9, const float* s10, const float* s11,
    u16* __restrict__ dst) {
  const int sizes[12] = {65536, 256, 65536, 256, 196608, 768,
                         65536, 256, 131072, 512, 131072, 256};
  const float* srcs[12] = {s0, s1, s2, s3, s4, s5, s6, s7, s8, s9, s10, s11};
  int gid = (blockIdx.x * 256 + threadIdx.x) * 4;
  if (gid >= W_TOTAL) return;
  int seg = 0, off = gid;
  while (off >= sizes[seg]) { off -= sizes[seg]; seg++; }
  const float4 v = *(const float4*)(srcs[seg] + off);
  ushort4 o;
  o.x = f2b(v.x); o.y = f2b(v.y); o.z = f2b(v.z); o.w = f2b(v.w);
  *(ushort4*)(dst + gid) = o;
}

// ---------------------------------------------------------------------------
// Edge aggregation: per-graph CSR in LDS, z = h + segment_sum(h[src], dst).
// ---------------------------------------------------------------------------
__global__ __launch_bounds__(256) void agg_kernel(
    const u16* __restrict__ h, const int* __restrict__ esrc,
    const int* __restrict__ edst, u16* __restrict__ z) {
  __shared__ int s_src[EPG_];
  __shared__ int s_cnt[N_];
  __shared__ int s_off[N_ + 1];
  __shared__ int s_pos[N_];
  const int g = blockIdx.x;
  const int t = threadIdx.x;

  if (t < N_) s_cnt[t] = 0;
  __syncthreads();

  int dst_loc[4], src_glob[4];
  const int ebase = g * EPG_;
#pragma unroll
  for (int i = 0; i < 4; i++) {
    const int e = ebase + t + i * 256;
    src_glob[i] = esrc[e];
    dst_loc[i] = edst[e] - g * N_;
    atomicAdd(&s_cnt[dst_loc[i]], 1);
  }
  __syncthreads();
  if (t == 0) {
    int acc = 0;
    for (int i = 0; i < N_; i++) { s_off[i] = acc; acc += s_cnt[i]; }
    s_off[N_] = acc;
  }
  __syncthreads();
  if (t < N_) s_pos[t] = s_off[t];
  __syncthreads();
#pragma unroll
  for (int i = 0; i < 4; i++) {
    const int slot = atomicAdd(&s_pos[dst_loc[i]], 1);
    s_src[slot] = src_glob[i];
  }
  __syncthreads();

  const int col = t;
  for (int i = 0; i < N_; i++) {
    const int row = g * N_ + i;
    float acc = b2f(h[(size_t)row * H_ + col]);
    const int e0 = s_off[i], e1 = s_off[i + 1];
    for (int e = e0; e < e1; e++)
      acc += b2f(h[(size_t)s_src[e] * H_ + col]);
    z[(size_t)row * H_ + col] = f2b(acc);
  }
}

// ---------------------------------------------------------------------------
// MFMA bf16 GEMM (m97 structure): C = act(A[R,K] @ W[NC,K]^T + bias) (+res)
// 128x128 tile, 256 thr = 4 waves (2x2), BK=64, global_load_lds 16B staging.
// ---------------------------------------------------------------------------
template <int NC, int K, int RELU, int RES, int STATS, int ASPLIT, int CMODE>
__global__ __launch_bounds__(256) void gemm_mfma(
    const u16* A, const u16* A2,
    const u16* __restrict__ W, const u16* __restrict__ bias,
    const u16* res, u16* C0, u16* C1, u16* C2,
    float* __restrict__ gsum, float* __restrict__ gsq) {
  __shared__ u16 As[128 * 64] __attribute__((aligned(16)));
  __shared__ u16 Bs[128 * 64] __attribute__((aligned(16)));

  const int t = threadIdx.x;
  const int wave = t >> 6, lane = t & 63;
  const int wr = wave >> 1, wc = wave & 1;
  const int quad = lane >> 4, ln15 = lane & 15;
  const int row0 = blockIdx.x * 128, col0 = blockIdx.y * 128;

  f32x4 acc[4][4];
#pragma unroll
  for (int i = 0; i < 4; i++)
#pragma unroll
    for (int j = 0; j < 4; j++) acc[i][j] = (f32x4){0.f, 0.f, 0.f, 0.f};

  for (int kt = 0; kt < K; kt += 64) {
    const u16* Ab;
    int kb, astr;
    if (ASPLIT) {
      if (kt < 256) { Ab = A; kb = kt; } else { Ab = A2; kb = kt - 256; }
      astr = 256;
    } else {
      Ab = A; kb = kt; astr = K;
    }
#pragma unroll
    for (int i = 0; i < 4; i++) {
      const int fid = t + i * 256;  // 0..1023: row = fid>>3, 16B seg = fid&7
      const u16* ga = Ab + (size_t)(row0 + (fid >> 3)) * astr + kb + (fid & 7) * 8;
      __builtin_amdgcn_global_load_lds(
          (const __attribute__((address_space(1))) void*)ga,
          (__attribute__((address_space(3))) void*)(As + fid * 8), 16, 0, 0);
      const u16* gw = W + (size_t)(col0 + (fid >> 3)) * K + kt + (fid & 7) * 8;
      __builtin_amdgcn_global_load_lds(
          (const __attribute__((address_space(1))) void*)gw,
          (__attribute__((address_space(3))) void*)(Bs + fid * 8), 16, 0, 0);
    }
    __syncthreads();
#pragma unroll
    for (int ks = 0; ks < 64; ks += 32) {
      s16x8 af[4], bf[4];
#pragma unroll
      for (int i = 0; i < 4; i++)
        af[i] = *(const s16x8*)(As + (wr * 64 + i * 16 + ln15) * 64 + ks + quad * 8);
#pragma unroll
      for (int j = 0; j < 4; j++)
        bf[j] = *(const s16x8*)(Bs + (wc * 64 + j * 16 + ln15) * 64 + ks + quad * 8);
#pragma unroll
      for (int i = 0; i < 4; i++)
#pragma unroll
        for (int j = 0; j < 4; j++)
          acc[i][j] = __builtin_amdgcn_mfma_f32_16x16x32_bf16(af[i], bf[j], acc[i][j], 0, 0, 0);
    }
    __syncthreads();
  }

  // ---- epilogue ----
  const int cbase = col0 + wc * 64;  // + j*16 + ln15 = global col
  u16* Cb;
  int coff, cstr;
  if (CMODE) {
    const int chunk = col0 >> 8;
    Cb = (chunk == 0) ? C0 : ((chunk == 1) ? C1 : C2);
    coff = (col0 & 255) + wc * 64;
    cstr = 256;
  } else {
    Cb = C0; coff = cbase; cstr = NC;
  }

  float bs[4];
#pragma unroll
  for (int j = 0; j < 4; j++) bs[j] = b2f(bias[cbase + j * 16 + ln15]);

  float ssum[4] = {}, ssq[4] = {};
#pragma unroll
  for (int i = 0; i < 4; i++) {
    const int rbase = row0 + wr * 64 + i * 16 + quad * 4;
#pragma unroll
    for (int reg = 0; reg < 4; reg++) {
      const int row = rbase + reg;
#pragma unroll
      for (int j = 0; j < 4; j++) {
        float val = acc[i][j][reg] + bs[j];
        if (RELU) val = fmaxf(val, 0.f);
        if (RES) val += b2f(res[(size_t)row * 256 + cbase + j * 16 + ln15]);
        Cb[(size_t)row * cstr + coff + j * 16 + ln15] = f2b(val);
        if (STATS) { ssum[j] += val; ssq[j] += val * val; }
      }
    }
  }

  if (STATS) {
#pragma unroll
    for (int j = 0; j < 4; j++) {
      float s = ssum[j];
      s += __shfl_xor(s, 16);
      s += __shfl_xor(s, 32);
      float q = ssq[j];
      q += __shfl_xor(q, 16);
      q += __shfl_xor(q, 32);
      if (lane < 16) {
        atomicAdd(&gsum[cbase + j * 16 + lane], s);
        atomicAdd(&gsq[cbase + j * 16 + lane], q);
      }
    }
  }
}

// ---------------------------------------------------------------------------
// MFMA attention: one block per (graph, head), 4 waves; wave owns a 32-row
// Q strip. QK^T and PV via 16x16x32 bf16 MFMA; softmax in registers on the
// C-layout fragments (row = quad*4+reg, reduce across ln15 via shfl_xor).
// P round-trips through LDS (C-layout -> A-layout), aliasing dead Q/K space.
// o may alias q (staged fully before any write). Pad strides chosen for
// 16B-aligned ds_read_b128 and <=2 lanes/bank (free).
// ---------------------------------------------------------------------------
__global__ __launch_bounds__(256) void attn_mfma(
    const u16* q, const u16* __restrict__ k,
    const u16* __restrict__ v, u16* o) {
  __shared__ u16 lds[21760] __attribute__((aligned(16)));
  u16* Vt = lds;                   // [32][136]  V transposed (d-major)
  u16* Qs = lds + 4352;            // [128][40]  scaled Q
  u16* Ks = lds + 4352 + 5120;     // [128][40]
  u16* P  = lds + 4352;            // [128][136] aliases Qs/Ks after barrier

  const int g = blockIdx.x >> 3;
  const int hd = blockIdx.x & 7;
  const int t = threadIdx.x;
  const int wave = t >> 6, lane = t & 63;
  const int quad = lane >> 4, ln15 = lane & 15;
  const int strip = wave * 32;
  const float scale = 0.1767766952966369f;  // 1/sqrt(32)

  // ---- stage Q (pre-scaled), K, V^T ----
#pragma unroll
  for (int i = 0; i < 4; i++) {
    const int fid = t + i * 256;   // 0..1023
    const int row = fid >> 3;
    const int seg = fid & 7;       // 4 u16 each
    const size_t gidx = (size_t)(g * N_ + row) * H_ + hd * HD_ + seg * 4;
    const ushort4 qv = *(const ushort4*)(q + gidx);
    const ushort4 kv = *(const ushort4*)(k + gidx);
    const ushort4 vv = *(const ushort4*)(v + gidx);
    ushort4 qs;
    qs.x = f2b(b2f(qv.x) * scale); qs.y = f2b(b2f(qv.y) * scale);
    qs.z = f2b(b2f(qv.z) * scale); qs.w = f2b(b2f(qv.w) * scale);
    *(ushort4*)(Qs + row * 40 + seg * 4) = qs;
    *(ushort4*)(Ks + row * 40 + seg * 4) = kv;
    Vt[(seg * 4 + 0) * 136 + row] = vv.x;
    Vt[(seg * 4 + 1) * 136 + row] = vv.y;
    Vt[(seg * 4 + 2) * 136 + row] = vv.z;
    Vt[(seg * 4 + 3) * 136 + row] = vv.w;
  }
  __syncthreads();

  // ---- S = Q K^T (strip x 128), fp32 accumulators in C-layout ----
  s16x8 af[2], bf[8];
#pragma unroll
  for (int mi = 0; mi < 2; mi++)
    af[mi] = *(const s16x8*)(Qs + (strip + mi * 16 + ln15) * 40 + quad * 8);
#pragma unroll
  for (int nj = 0; nj < 8; nj++)
    bf[nj] = *(const s16x8*)(Ks + (nj * 16 + ln15) * 40 + quad * 8);

  f32x4 acc[2][8];
#pragma unroll
  for (int mi = 0; mi < 2; mi++)
#pragma unroll
    for (int nj = 0; nj < 8; nj++)
      acc[mi][nj] = __builtin_amdgcn_mfma_f32_16x16x32_bf16(
          af[mi], bf[nj], (f32x4){0.f, 0.f, 0.f, 0.f}, 0, 0, 0);

  __syncthreads();  // Q/K dead; region becomes P

  // ---- softmax per row (row = strip + mi*16 + quad*4 + reg), write P ----
#pragma unroll
  for (int mi = 0; mi < 2; mi++) {
#pragma unroll
    for (int reg = 0; reg < 4; reg++) {
      float mx = acc[mi][0][reg];
#pragma unroll
      for (int j = 1; j < 8; j++) mx = fmaxf(mx, acc[mi][j][reg]);
      mx = fmaxf(mx, __shfl_xor(mx, 1));
      mx = fmaxf(mx, __shfl_xor(mx, 2));
      mx = fmaxf(mx, __shfl_xor(mx, 4));
      mx = fmaxf(mx, __shfl_xor(mx, 8));
      float e[8], s = 0.f;
#pragma unroll
      for (int j = 0; j < 8; j++) { e[j] = __expf(acc[mi][j][reg] - mx); s += e[j]; }
      s += __shfl_xor(s, 1);
      s += __shfl_xor(s, 2);
      s += __shfl_xor(s, 4);
      s += __shfl_xor(s, 8);
      const float inv = 1.f / s;
      const int prow = strip + mi * 16 + quad * 4 + reg;
#pragma unroll
      for (int j = 0; j < 8; j++)
        P[prow * 136 + j * 16 + ln15] = f2b(e[j] * inv);
    }
  }
  __syncthreads();

  // ---- O = P V (strip x 32) ----
  f32x4 acc2[2][2];
#pragma unroll
  for (int mi = 0; mi < 2; mi++)
#pragma unroll
    for (int nj = 0; nj < 2; nj++) acc2[mi][nj] = (f32x4){0.f, 0.f, 0.f, 0.f};
#pragma unroll
  for (int kt = 0; kt < 4; kt++) {
    s16x8 paf[2], vbf[2];
#pragma unroll
    for (int mi = 0; mi < 2; mi++)
      paf[mi] = *(const s16x8*)(P + (strip + mi * 16 + ln15) * 136 + kt * 32 + quad * 8);
#pragma unroll
    for (int nj = 0; nj < 2; nj++)
      vbf[nj] = *(const s16x8*)(Vt + (nj * 16 + ln15) * 136 + kt * 32 + quad * 8);
#pragma unroll
    for (int mi = 0; mi < 2; mi++)
#pragma unroll
      for (int nj = 0; nj < 2; nj++)
        acc2[mi][nj] = __builtin_amdgcn_mfma_f32_16x16x32_bf16(
            paf[mi], vbf[nj], acc2[mi][nj], 0, 0, 0);
  }

#pragma unroll
  for (int mi = 0; mi < 2; mi++)
#pragma unroll
    for (int nj = 0; nj < 2; nj++)
#pragma unroll
      for (int reg = 0; reg < 4; reg++) {
        const int row = strip + mi * 16 + quad * 4 + reg;
        o[(size_t)(g * N_ + row) * H_ + hd * HD_ + nj * 16 + ln15] =
            f2b(acc2[mi][nj][reg]);
      }
}

// BN finalize: a = g*rsqrt(var+eps); b' = b - mean*a   (fp32 params)
__global__ void bn_finalize(const float* __restrict__ sum,
                            const float* __restrict__ sq,
                            const float* __restrict__ g,
                            const float* __restrict__ bb,
                            float* __restrict__ a, float* __restrict__ b) {
  const int c = threadIdx.x;
  const float mean = sum[c] * (1.f / R_);
  const float var = fmaxf(sq[c] * (1.f / R_) - mean * mean, 0.f);
  const float ai = g[c] * rsqrtf(var + 1e-5f);
  a[c] = ai;
  b[c] = bb[c] - mean * ai;
}

// x = bn_local(r_local) + bn_attn(r_attn)   (bf16 in/out)
__global__ __launch_bounds__(256) void combine_kernel(
    const u16* __restrict__ rl, const u16* __restrict__ ra,
    const float* __restrict__ st, u16* __restrict__ x) {
  const size_t i = (size_t)blockIdx.x * 256 + threadIdx.x;  // 4-elem group idx
  const int col = (int)(i & 63) * 4;
  float rl4[4], ra4[4];
  ld4b(rl + i * 4, rl4);
  ld4b(ra + i * 4, ra4);
  const float* al = st + 1536;
  const float* bl = st + 1792;
  const float* aa = st + 2048;
  const float* ba = st + 2304;
  ushort4 o;
  u16* ov = (u16*)&o;
#pragma unroll
  for (int j = 0; j < 4; j++)
    ov[j] = f2b(al[col + j] * rl4[j] + bl[col + j] + aa[col + j] * ra4[j] + ba[col + j]);
  *(ushort4*)(x + i * 4) = o;
}

// out = bn_out(y): bf16 y -> fp32 out
__global__ __launch_bounds__(256) void final_kernel(
    const u16* __restrict__ y, const float* __restrict__ st,
    float* __restrict__ out) {
  const size_t i = (size_t)blockIdx.x * 256 + threadIdx.x;
  const int col = (int)(i & 63) * 4;
  float y4[4];
  ld4b(y + i * 4, y4);
  const float* ao = st + 2560;
  const float* bo = st + 2816;
  float4 o;
  o.x = ao[col + 0] * y4[0] + bo[col + 0];
  o.y = ao[col + 1] * y4[1] + bo[col + 1];
  o.z = ao[col + 2] * y4[2] + bo[col + 2];
  o.w = ao[col + 3] * y4[3] + bo[col + 3];
  *(float4*)(out + i * 4) = o;
}

extern "C" void kernel_launch(void* const* d_in, const int* in_sizes, int n_in,
                              void* d_out, int out_size, void* d_ws, size_t ws_size,
                              hipStream_t stream) {
  const float* h = (const float*)d_in[0];
  const int* esrc = (const int*)d_in[1];
  const int* edst = (const int*)d_in[2];
  const float* bn_local_g = (const float*)d_in[11];
  const float* bn_local_b = (const float*)d_in[12];
  const float* bn_attn_g = (const float*)d_in[13];
  const float* bn_attn_b = (const float*)d_in[14];
  const float* bn_out_g = (const float*)d_in[15];
  const float* bn_out_b = (const float*)d_in[16];

  const size_t RH = (size_t)R_ * H_;
  float* stats = (float*)d_ws;                        // 3072 floats
  u16* WB = (u16*)((char*)d_ws + 65536);              // packed bf16 weights ~1.3 MB
  u16* Hb = (u16*)((char*)d_ws + 65536 + 2097152);    // h in bf16, 32 MB
  u16* S1 = Hb + RH;                                  // 32 MB
  u16* S2 = S1 + RH;                                  // 32 MB
  u16* OD = (u16*)d_out;                              // first 32 MB of d_out as bf16 scratch
  float* outf = (float*)d_out;                        // final fp32 out (64 MB)

  zero_stats<<<12, 256, 0, stream>>>(stats);
  cvt_h<<<(int)(RH / 4 / 256), 256, 0, stream>>>(h, Hb);
  cvt_w<<<(W_TOTAL / 4 + 255) / 256, 256, 0, stream>>>(
      (const float*)d_in[3], (const float*)d_in[4], (const float*)d_in[5],
      (const float*)d_in[6], (const float*)d_in[7], (const float*)d_in[8],
      (const float*)d_in[9], (const float*)d_in[10], (const float*)d_in[17],
      (const float*)d_in[18], (const float*)d_in[19], (const float*)d_in[20], WB);

  // qkv fused: [R,768] -> q=S1, k=S2, v=OD
  gemm_mfma<768, 256, 0, 0, 0, 0, 1><<<dim3(512, 6), 256, 0, stream>>>(
      Hb, nullptr, WB + OFF_AIW, WB + OFF_AIB, nullptr, S1, S2, OD, nullptr, nullptr);
  // o = softmax(q k^T / sqrt(32)) v, in-place over q (S1)
  attn_mfma<<<B_ * NH_, 256, 0, stream>>>(S1, S2, OD, S1);
  // r_attn = h + o@Wo^T -> S2, + stats_attn
  gemm_mfma<256, 256, 0, 1, 1, 0, 0><<<dim3(512, 2), 256, 0, stream>>>(
      S1, nullptr, WB + OFF_AOW, WB + OFF_AOB, Hb, S2, nullptr, nullptr,
      stats + 512, stats + 768);
  // z = h + segment_sum -> OD
  agg_kernel<<<B_, 256, 0, stream>>>(Hb, esrc, edst, OD);
  // t1 = relu(z@W1^T) -> S1
  gemm_mfma<256, 256, 1, 0, 0, 0, 0><<<dim3(512, 2), 256, 0, stream>>>(
      OD, nullptr, WB + OFF_GW1, WB + OFF_GB1, nullptr, S1, nullptr, nullptr,
      nullptr, nullptr);
  // r_local = h + t1@W2^T -> OD, + stats_local
  gemm_mfma<256, 256, 0, 1, 1, 0, 0><<<dim3(512, 2), 256, 0, stream>>>(
      S1, nullptr, WB + OFF_GW2, WB + OFF_GB2, Hb, OD, nullptr, nullptr,
      stats + 0, stats + 256);

  bn_finalize<<<1, 256, 0, stream>>>(stats + 0, stats + 256, bn_local_g,
                                     bn_local_b, stats + 1536, stats + 1792);
  bn_finalize<<<1, 256, 0, stream>>>(stats + 512, stats + 768, bn_attn_g,
                                     bn_attn_b, stats + 2048, stats + 2304);

  // x = bn_l(r_local OD) + bn_a(r_attn S2) -> S1
  combine_kernel<<<(int)(RH / 4 / 256), 256, 0, stream>>>(OD, S2, stats, S1);
  // t2 = relu(x@F1^T) [R,512]: lo -> S2, hi -> OD
  gemm_mfma<512, 256, 1, 0, 0, 0, 1><<<dim3(512, 4), 256, 0, stream>>>(
      S1, nullptr, WB + OFF_F1W, WB + OFF_F1B, nullptr, S2, OD, nullptr,
      nullptr, nullptr);
  // y = x + t2@F2^T -> S1 in place, + stats_out
  gemm_mfma<256, 512, 0, 1, 1, 1, 0><<<dim3(512, 2), 256, 0, stream>>>(
      S2, OD, WB + OFF_F2W, WB + OFF_F2B, S1, S1, nullptr, nullptr,
      stats + 1024, stats + 1280);

  bn_finalize<<<1, 256, 0, stream>>>(stats + 1024, stats + 1280, bn_out_g,
                                     bn_out_b, stats + 2560, stats + 2816);
  // out = bn_out(y S1) -> fp32 d_out
  final_kernel<<<(int)(RH / 4 / 256), 256, 0, stream>>>(S1, stats, outf);
}